// Round 1
// baseline (309.578 us; speedup 1.0000x reference)
//
#include <hip/hip_runtime.h>

// ElectrostaticEnergyLayer: per-pair shielded/switched Coulomb energy,
// scatter-added to atoms by idx_i.
//
// R9: (a) ee_acc was ~115us hidden cost: 256 blocks = 1/CU = 25% occupancy,
// serial load->atomic loop, and ~13% pad entries all hammering acc[0]
// (same-address LDS-atomic serialization). Fix: SCH 2->8 (1024 blocks,
// 4/CU), 2-stage prefetch pipeline, pad entries spread over li (v=0).
// (b) ee_bin VGPR_Count=36 proved the 16-pair MLP never materialized
// (needs >=48 VGPRs) -- the j4-load->gather interleave serialized. Fix:
// issue all 12 stream loads, then all 16 gathers; move lcur init/barrier
// after load issue. (c) pad granularity 16->4 + CAP 126976->114688 keeps
// workspace byte-identical (67,117,056 B) so the fast path always engages.
// Fast math: v_rcp/v_rsq builtins; Es = rsq*(1+0.01*(d^2+1))-0.2 (no sqrt,
// no div; rel err ~1e-5 vs 0.33 abs threshold).

#define KEHALF 7.199822675975274f
#define NB    128            // buckets
#define BSH   11             // atoms per bucket = 2048
#define BMASK 2047
#define CAP   114688         // entries per bucket region (list = 56 MiB)
#define CURSTRIDE 16         // cursors 64 B apart
#define SCH   8              // phase-2 chunks per bucket
#define SCAP  72             // LDS staging slots per bucket per block (36 KiB)
#define VSCALE 524288.0f     // 2^19; |Qj*R| <= ~1.2 -> |v| < 2^20
#define VINV   (1.0f / 524288.0f)
#define P1B   512            // phase-1 block threads
#define P1PAIRS 8192         // pairs per phase-1 block (512 thr x 16)

// radial factor R(d) via fast rcp/rsq: E = KEHALF * Qi * Qj * R(d)
__device__ __forceinline__ float radial_fast(float d) {
    float d2p1 = d * d + 1.0f;
    float rsq  = __builtin_amdgcn_rsqf(d2p1);          // 1/sqrt(d^2+1)
    float x    = 0.5f * d;
    float sw   = (x < 1.0f) ? 1.0f - x * x * x * (x * (6.0f * x - 15.0f) + 10.0f)
                            : 0.0f;
    float Eo = __builtin_amdgcn_rcpf(d) + d * 0.01f - 0.2f;
    float Es = rsq * (1.0f + 0.01f * d2p1) - 0.2f;     // 1/dsh + dsh/100
    return sw * Es + (1.0f - sw) * Eo;
}

// ---------------- Phase 1: LDS-staged binning, batched gathers ------------
__global__ __launch_bounds__(P1B, 4) void ee_bin(
    const float* __restrict__ Dij,
    const float* __restrict__ Qa,
    const int*   __restrict__ idx_i,
    const int*   __restrict__ idx_j,
    unsigned int* __restrict__ list,    // NB * CAP packed entries
    unsigned int* __restrict__ gcur,    // NB cursors, stride CURSTRIDE
    float*        __restrict__ out)     // spill target (pre-zeroed)
{
    __shared__ unsigned int stage[NB * SCAP];   // 36 KiB
    __shared__ int lcur[NB];
    __shared__ int gofs[NB];
    int tid = threadIdx.x;

    long blockBase = (long)blockIdx.x * P1PAIRS;

    // 1) issue ALL stream loads first (12 x dwordx4 in flight), ...
    int4 j4[4];
#pragma unroll
    for (int g = 0; g < 4; ++g)
        j4[g] = *reinterpret_cast<const int4*>(
            idx_j + blockBase + (long)(g * P1B + tid) * 4);
    float4 d4[4];
    int4   i4[4];
#pragma unroll
    for (int g = 0; g < 4; ++g) {
        long o = blockBase + (long)(g * P1B + tid) * 4;
        d4[g] = *reinterpret_cast<const float4*>(Dij + o);
        i4[g] = *reinterpret_cast<const int4*>(idx_i + o);
    }
    // ... then ALL 16 Qj gathers back-to-back (only j4 must land first)
    float QJ[16];
#pragma unroll
    for (int g = 0; g < 4; ++g) {
        QJ[g * 4 + 0] = Qa[j4[g].x];
        QJ[g * 4 + 1] = Qa[j4[g].y];
        QJ[g * 4 + 2] = Qa[j4[g].z];
        QJ[g * 4 + 3] = Qa[j4[g].w];
    }

    // LDS init happens while loads are in flight
    if (tid < NB) lcur[tid] = 0;
    __syncthreads();

    // 2) compute + stage
#pragma unroll
    for (int g = 0; g < 4; ++g) {
        float dd[4] = {d4[g].x, d4[g].y, d4[g].z, d4[g].w};
        int   ii[4] = {i4[g].x, i4[g].y, i4[g].z, i4[g].w};
#pragma unroll
        for (int k = 0; k < 4; ++k) {
            float d = dd[k];
            if (d <= 10.0f) {
                float w = QJ[g * 4 + k] * radial_fast(d);   // deferred Qi
                int v = __float2int_rn(w * VSCALE);
                int b  = ii[k] >> BSH;
                int li = ii[k] & BMASK;
                int slot = atomicAdd(&lcur[b], 1);
                if (slot < SCAP) {
                    stage[b * SCAP + slot] =
                        ((unsigned int)li << 21) | ((unsigned int)v & 0x1FFFFFu);
                } else {
                    // rare (~1e3/launch at SCAP=72): exact float spill
                    atomicAdd(out + ii[k], KEHALF * Qa[ii[k]] * w);
                }
            }
        }
    }
    __syncthreads();

    // one padded (4-entry = 16 B multiple) reservation per (block, bucket)
    if (tid < NB) {
        int n = lcur[tid];
        if (n > SCAP) n = SCAP;
        lcur[tid] = n;                          // clamp for copy-out
        int padded = (n + 3) & ~3;
        gofs[tid] = (int)atomicAdd(&gcur[tid * CURSTRIDE], (unsigned int)padded);
    }
    __syncthreads();

    // coalesced copy-out: wave w handles buckets w, w+8, ...
    int wave = tid >> 6, lane = tid & 63;
    for (int b = wave; b < NB; b += (P1B / 64)) {
        int n = lcur[b];
        int padded = (n + 3) & ~3;
        int go = gofs[b];
        long rb = (long)b * CAP;
        for (int i = lane; i < padded; i += 64) {
            // pad entries: v=0, li spread across banks (no acc[0] hammering)
            unsigned int val = (i < n) ? stage[b * SCAP + i]
                                       : ((unsigned int)(i & BMASK) << 21);
            int pos = go + i;
            if (pos < CAP)                       // statistical hard guard
                list[rb + pos] = val;
        }
    }
}

// ---------------- Phase 2: per-bucket-chunk LDS int accumulation ----------
__global__ __launch_bounds__(512) void ee_acc(
    const unsigned int* __restrict__ list,
    const unsigned int* __restrict__ gcur,
    int* __restrict__ partials)          // [NB*SCH][2048]
{
    __shared__ int acc[1 << BSH];
    int b = blockIdx.x / SCH;            // SCH=8: pow2, cheap
    int s = blockIdx.x % SCH;
    int t = threadIdx.x;
#pragma unroll
    for (int r = 0; r < (1 << BSH) / 512; ++r) acc[t + r * 512] = 0;
    __syncthreads();

    int n = (int)gcur[b * CURSTRIDE];    // padded total, multiple of 4
    if (n > CAP) n = CAP;
    int nq = n >> 2;                     // uint4 count
    int per = (nq + SCH - 1) / SCH;
    int q0 = s * per;
    int q1 = q0 + per; if (q1 > nq) q1 = nq;

    const uint4* lp4 = reinterpret_cast<const uint4*>(list + (long)b * CAP);
    int q = q0 + t;
    if (q < q1) {
        // 2-stage software pipeline: next load in flight over current atomics
        uint4 u = lp4[q];
        for (q += 512; q < q1; q += 512) {
            uint4 nx = lp4[q];
            unsigned int us[4] = {u.x, u.y, u.z, u.w};
#pragma unroll
            for (int k = 0; k < 4; ++k) {
                unsigned int e = us[k];
                int li = (int)(e >> 21);
                int v  = ((int)(e << 11)) >> 11;   // sign-extend 21-bit payload
                atomicAdd(&acc[li], v);            // native ds_add_u32
            }
            u = nx;
        }
        unsigned int us[4] = {u.x, u.y, u.z, u.w};
#pragma unroll
        for (int k = 0; k < 4; ++k) {
            unsigned int e = us[k];
            int li = (int)(e >> 21);
            int v  = ((int)(e << 11)) >> 11;
            atomicAdd(&acc[li], v);
        }
    }
    __syncthreads();

    int* pp = partials + ((long)b * SCH + s) * (1 << BSH);
#pragma unroll
    for (int r = 0; r < (1 << BSH) / 512; ++r) pp[t + r * 512] = acc[t + r * 512];
}

// ---------------- Phase 3: combine partials, apply KEHALF*Qi, add spill ----
__global__ __launch_bounds__(256) void ee_final(
    const int* __restrict__ partials,
    const float* __restrict__ Qa,
    float* __restrict__ out, int nAtoms)
{
    int q = blockIdx.x * blockDim.x + threadIdx.x;      // one int4 per thread
    int n4 = nAtoms >> 2;
    if (q >= n4) return;
    int a0 = q << 2;
    int b  = a0 >> BSH;
    int li = a0 & BMASK;
    long base = (long)(b * SCH) * (1 << BSH) + li;
    int4 s = {0, 0, 0, 0};
#pragma unroll
    for (int r = 0; r < SCH; ++r) {
        int4 p = *reinterpret_cast<const int4*>(partials + base + (long)r * (1 << BSH));
        s.x += p.x; s.y += p.y; s.z += p.z; s.w += p.w;
    }
    float4 qv = reinterpret_cast<const float4*>(Qa)[q];
    float4 sp = reinterpret_cast<const float4*>(out)[q];   // spill (or 0)
    float4 o;
    o.x = KEHALF * qv.x * ((float)s.x * VINV) + sp.x;
    o.y = KEHALF * qv.y * ((float)s.y * VINV) + sp.y;
    o.z = KEHALF * qv.z * ((float)s.z * VINV) + sp.z;
    o.w = KEHALF * qv.w * ((float)s.w * VINV) + sp.w;
    reinterpret_cast<float4*>(out)[q] = o;
}

// ---------------- Fallback: int fixed-point global atomics (R3) --------
#define FP_SCALE 4194304.0f
#define FP_INV   (1.0f / 4194304.0f)

__device__ __forceinline__ float radial_exact(float d) {
    float dsh = sqrtf(d * d + 1.0f);
    float x   = 0.5f * d;
    float sw  = (x < 1.0f) ? 1.0f - x * x * x * (x * (6.0f * x - 15.0f) + 10.0f)
                           : 0.0f;
    float Eo = 1.0f / d   + d   * 0.01f - 0.2f;
    float Es = 1.0f / dsh + dsh * 0.01f - 0.2f;
    return sw * Es + (1.0f - sw) * Eo;
}

__global__ __launch_bounds__(256) void ee_pair_fix(
    const float* __restrict__ Dij,
    const float* __restrict__ Qa,
    const int*   __restrict__ idx_i,
    const int*   __restrict__ idx_j,
    int*         __restrict__ acc,
    int P)
{
    long base = ((long)blockIdx.x * blockDim.x + threadIdx.x) * 4;
    if (base >= P) return;
    float4 d4 = *reinterpret_cast<const float4*>(Dij + base);
    int4   i4 = *reinterpret_cast<const int4*>(idx_i + base);
    int4   j4 = *reinterpret_cast<const int4*>(idx_j + base);
    float D[4]  = {d4.x, d4.y, d4.z, d4.w};
    int   ii[4] = {i4.x, i4.y, i4.z, i4.w};
    int   jj[4] = {j4.x, j4.y, j4.z, j4.w};
#pragma unroll
    for (int k = 0; k < 4; ++k) {
        float d = D[k];
        if (d > 10.0f) continue;
        float e = KEHALF * Qa[ii[k]] * Qa[jj[k]] * radial_exact(d);
        atomicAdd(acc + ii[k], __float2int_rn(e * FP_SCALE));
    }
}

__global__ __launch_bounds__(256) void ee_convert(
    const int* __restrict__ acc, float* __restrict__ out, int nAtoms)
{
    int n4 = nAtoms >> 2;
    int q = blockIdx.x * blockDim.x + threadIdx.x;
    if (q >= n4) return;
    int4 a = reinterpret_cast<const int4*>(acc)[q];
    float4 o;
    o.x = (float)a.x * FP_INV;
    o.y = (float)a.y * FP_INV;
    o.z = (float)a.z * FP_INV;
    o.w = (float)a.w * FP_INV;
    reinterpret_cast<float4*>(out)[q] = o;
}

__global__ __launch_bounds__(256) void ee_pair_direct(
    const float* __restrict__ Dij,
    const float* __restrict__ Qa,
    const int*   __restrict__ idx_i,
    const int*   __restrict__ idx_j,
    float*       __restrict__ out,
    int P)
{
    long t = (long)blockIdx.x * blockDim.x + threadIdx.x;
    if (t >= P) return;
    float d = Dij[t];
    if (d > 10.0f) return;
    atomicAdd(out + idx_i[t], KEHALF * Qa[idx_i[t]] * Qa[idx_j[t]] * radial_exact(d));
}

extern "C" void kernel_launch(void* const* d_in, const int* in_sizes, int n_in,
                              void* d_out, int out_size, void* d_ws, size_t ws_size,
                              hipStream_t stream) {
    const float* Dij   = (const float*)d_in[0];
    const float* Qa    = (const float*)d_in[1];
    const int*   idx_i = (const int*)d_in[2];
    const int*   idx_j = (const int*)d_in[3];
    float*       out   = (float*)d_out;

    int P      = in_sizes[0];
    int nAtoms = in_sizes[1];

    size_t listBytes = (size_t)NB * CAP * sizeof(unsigned int);          // 56 MiB
    size_t partBytes = (size_t)NB * SCH * (1 << BSH) * sizeof(int);      // 8 MiB
    size_t curBytes  = (size_t)NB * CURSTRIDE * sizeof(unsigned int);    // 8 KiB

    if (ws_size >= listBytes + partBytes + curBytes &&
        nAtoms == NB * (1 << BSH) && (P % P1PAIRS) == 0) {
        unsigned int* list = (unsigned int*)d_ws;
        int*          part = (int*)((char*)d_ws + listBytes);
        unsigned int* gcur = (unsigned int*)((char*)d_ws + listBytes + partBytes);
        hipMemsetAsync(gcur, 0, curBytes, stream);
        hipMemsetAsync(out, 0, (size_t)out_size * sizeof(float), stream); // spill base
        int grid1 = P / P1PAIRS;                                          // 2048
        ee_bin<<<grid1, P1B, 0, stream>>>(Dij, Qa, idx_i, idx_j, list, gcur, out);
        ee_acc<<<NB * SCH, 512, 0, stream>>>(list, gcur, part);
        ee_final<<<(nAtoms / 4 + 255) / 256, 256, 0, stream>>>(part, Qa, out, nAtoms);
    } else if (ws_size >= (size_t)nAtoms * sizeof(int) &&
               (nAtoms & 3) == 0 && (P & 3) == 0) {
        int* acc = (int*)d_ws;
        hipMemsetAsync(acc, 0, (size_t)nAtoms * sizeof(int), stream);
        int grid = (P / 4 + 255) / 256;
        ee_pair_fix<<<grid, 256, 0, stream>>>(Dij, Qa, idx_i, idx_j, acc, P);
        ee_convert<<<(nAtoms / 4 + 255) / 256, 256, 0, stream>>>(acc, out, nAtoms);
    } else {
        hipMemsetAsync(out, 0, (size_t)out_size * sizeof(float), stream);
        int grid = (P + 255) / 256;
        ee_pair_direct<<<grid, 256, 0, stream>>>(Dij, Qa, idx_i, idx_j, out, P);
    }
}

// Round 2
// 282.361 us; speedup vs baseline: 1.0964x; 1.0964x over previous
//
#include <hip/hip_runtime.h>

// ElectrostaticEnergyLayer: per-pair shielded/switched Coulomb energy,
// scatter-added to atoms by idx_i.
//
// R10: theory = ee_bin's 143us floor is the gcur reservation: 128 cursors
// x 2048 blocks of device-scope SAME-ADDRESS atomics, serialized at the
// coherence point (~70ns each -> ~143us chain), with every block barriered
// on its reservation. Fix: 8-way cursor replication by blockIdx&7 -- each
// bucket's region is pre-split into 8 sub-regions (RCAP) with independent
// cursors -> per-address queue depth 2048 -> 256 (deterministic split,
// 256 blocks per replica). Sub-region overflow (~3.5 sigma, <1 cell/launch
// expected) spills via exact float atomics decoded from the staged entry.
// ee_bin load/gather structure reverted to the exact R8 form (R9's batched
// gathers regressed 143->171, VGPR stuck at 40 => compiler re-serialized).
// Phase-2 block (b,s) consumes exactly sub-region s of bucket b (SCH=8).
// Workspace: 58,589,184 + 8,388,608 + 65,536 = 67,043,328 B <= known-good
// 67,117,056 B footprint, so the fast path always engages.
// Fast math: v_rcp/v_rsq builtins; Es = rsq*(1+0.01*(d^2+1))-0.2 (no sqrt,
// no div; rel err ~1e-5 vs 0.33 abs threshold).

#define KEHALF 7.199822675975274f
#define NB    128            // buckets
#define BSH   11             // atoms per bucket = 2048
#define BMASK 2047
#define NREP  8              // cursor/list replicas per bucket
#define RCAP  14304          // entries per (bucket, replica) sub-region
#define CAP   (NREP * RCAP)  // 114432 entries per bucket region (list ~55.9 MiB)
#define CURSTRIDE 16         // cursors 64 B apart
#define SCH   8              // phase-2 chunks per bucket ( == NREP )
#define SCAP  72             // LDS staging slots per bucket per block (36 KiB)
#define VSCALE 524288.0f     // 2^19; |Qj*R| <= ~1.2 -> |v| < 2^20
#define VINV   (1.0f / 524288.0f)
#define P1B   512            // phase-1 block threads
#define P1PAIRS 8192         // pairs per phase-1 block (512 thr x 16)

// radial factor R(d) via fast rcp/rsq: E = KEHALF * Qi * Qj * R(d)
__device__ __forceinline__ float radial_fast(float d) {
    float d2p1 = d * d + 1.0f;
    float rsq  = __builtin_amdgcn_rsqf(d2p1);          // 1/sqrt(d^2+1)
    float x    = 0.5f * d;
    float sw   = (x < 1.0f) ? 1.0f - x * x * x * (x * (6.0f * x - 15.0f) + 10.0f)
                            : 0.0f;
    float Eo = __builtin_amdgcn_rcpf(d) + d * 0.01f - 0.2f;
    float Es = rsq * (1.0f + 0.01f * d2p1) - 0.2f;     // 1/dsh + dsh/100
    return sw * Es + (1.0f - sw) * Eo;
}

// ---------------- Phase 1: LDS-staged binning (R8 structure) --------------
__global__ __launch_bounds__(P1B, 4) void ee_bin(
    const float* __restrict__ Dij,
    const float* __restrict__ Qa,
    const int*   __restrict__ idx_i,
    const int*   __restrict__ idx_j,
    unsigned int* __restrict__ list,    // NB * CAP packed entries
    unsigned int* __restrict__ gcur,    // NB*NREP cursors, stride CURSTRIDE
    float*        __restrict__ out)     // spill target (pre-zeroed)
{
    __shared__ unsigned int stage[NB * SCAP];   // 36 KiB
    __shared__ int lcur[NB];
    __shared__ int gofs[NB];
    int tid = threadIdx.x;
    if (tid < NB) lcur[tid] = 0;
    __syncthreads();

    long blockBase = (long)blockIdx.x * P1PAIRS;
    int rep = (int)(blockIdx.x & (NREP - 1));   // cursor/list replica

    float D[16];
    int   II[16];
    float QJ[16];

    // 1) stream loads + unconditional Qj gathers — R8-exact interleave
#pragma unroll
    for (int g = 0; g < 4; ++g) {
        long o = blockBase + ((long)(g * P1B + tid)) * 4;
        int4 j4 = *reinterpret_cast<const int4*>(idx_j + o);
        QJ[g * 4 + 0] = Qa[j4.x];
        QJ[g * 4 + 1] = Qa[j4.y];
        QJ[g * 4 + 2] = Qa[j4.z];
        QJ[g * 4 + 3] = Qa[j4.w];
        float4 d4 = *reinterpret_cast<const float4*>(Dij + o);
        int4   i4 = *reinterpret_cast<const int4*>(idx_i + o);
        D[g * 4 + 0] = d4.x; D[g * 4 + 1] = d4.y;
        D[g * 4 + 2] = d4.z; D[g * 4 + 3] = d4.w;
        II[g * 4 + 0] = i4.x; II[g * 4 + 1] = i4.y;
        II[g * 4 + 2] = i4.z; II[g * 4 + 3] = i4.w;
    }

    // 2) compute + stage
#pragma unroll
    for (int m = 0; m < 16; ++m) {
        float d = D[m];
        if (d <= 10.0f) {
            float w = QJ[m] * radial_fast(d);   // deferred Qi
            int v = __float2int_rn(w * VSCALE);
            int b  = II[m] >> BSH;
            int li = II[m] & BMASK;
            int slot = atomicAdd(&lcur[b], 1);
            if (slot < SCAP) {
                stage[b * SCAP + slot] =
                    ((unsigned int)li << 21) | ((unsigned int)v & 0x1FFFFFu);
            } else {
                // rare (~1e3/launch at SCAP=72): exact float spill
                atomicAdd(out + II[m], KEHALF * Qa[II[m]] * w);
            }
        }
    }
    __syncthreads();

    // one padded (4-entry = 16 B multiple) reservation per (block, bucket),
    // on this block's replica cursor: per-address contention = 256 blocks.
    if (tid < NB) {
        int n = lcur[tid];
        if (n > SCAP) n = SCAP;
        lcur[tid] = n;                          // clamp for copy-out
        int padded = (n + 3) & ~3;
        gofs[tid] = (int)atomicAdd(&gcur[(tid * NREP + rep) * CURSTRIDE],
                                   (unsigned int)padded);
    }
    __syncthreads();

    // coalesced copy-out: wave w handles buckets w, w+8, ...
    int wave = tid >> 6, lane = tid & 63;
    for (int b = wave; b < NB; b += (P1B / 64)) {
        int n = lcur[b];
        int padded = (n + 3) & ~3;
        int go = gofs[b];
        long rb = (long)b * CAP + (long)rep * RCAP;
        for (int i = lane; i < padded; i += 64) {
            // pad entries: v=0, li spread (no acc[0] hammering in phase 2)
            unsigned int val = (i < n) ? stage[b * SCAP + i]
                                       : ((unsigned int)(i & BMASK) << 21);
            int pos = go + i;
            if (pos < RCAP) {
                list[rb + pos] = val;
            } else if (i < n) {
                // sub-region overflow (stat. ~never): decode + float spill
                int atom = (b << BSH) | (int)(val >> 21);
                int v    = ((int)(val << 11)) >> 11;
                atomicAdd(out + atom, KEHALF * Qa[atom] * ((float)v * VINV));
            }
        }
    }
}

// ---------------- Phase 2: per-(bucket,replica) LDS int accumulation ------
__global__ __launch_bounds__(512) void ee_acc(
    const unsigned int* __restrict__ list,
    const unsigned int* __restrict__ gcur,
    int* __restrict__ partials)          // [NB*SCH][2048]
{
    __shared__ int acc[1 << BSH];
    int b = blockIdx.x >> 3;             // SCH == NREP == 8
    int s = blockIdx.x & 7;
    int t = threadIdx.x;
#pragma unroll
    for (int r = 0; r < (1 << BSH) / 512; ++r) acc[t + r * 512] = 0;
    __syncthreads();

    int n = (int)gcur[(b * NREP + s) * CURSTRIDE];  // padded, multiple of 4
    if (n > RCAP) n = RCAP;
    int nq = n >> 2;                     // uint4 count

    const uint4* lp4 =
        reinterpret_cast<const uint4*>(list + (long)b * CAP + (long)s * RCAP);
    int q = t;
    if (q < nq) {
        // 2-stage software pipeline: next load in flight over current atomics
        uint4 u = lp4[q];
        for (q += 512; q < nq; q += 512) {
            uint4 nx = lp4[q];
            unsigned int us[4] = {u.x, u.y, u.z, u.w};
#pragma unroll
            for (int k = 0; k < 4; ++k) {
                unsigned int e = us[k];
                int li = (int)(e >> 21);
                int v  = ((int)(e << 11)) >> 11;   // sign-extend 21-bit payload
                atomicAdd(&acc[li], v);            // native ds_add_u32
            }
            u = nx;
        }
        unsigned int us[4] = {u.x, u.y, u.z, u.w};
#pragma unroll
        for (int k = 0; k < 4; ++k) {
            unsigned int e = us[k];
            int li = (int)(e >> 21);
            int v  = ((int)(e << 11)) >> 11;
            atomicAdd(&acc[li], v);
        }
    }
    __syncthreads();

    int* pp = partials + ((long)b * SCH + s) * (1 << BSH);
#pragma unroll
    for (int r = 0; r < (1 << BSH) / 512; ++r) pp[t + r * 512] = acc[t + r * 512];
}

// ---------------- Phase 3: combine partials, apply KEHALF*Qi, add spill ----
__global__ __launch_bounds__(256) void ee_final(
    const int* __restrict__ partials,
    const float* __restrict__ Qa,
    float* __restrict__ out, int nAtoms)
{
    int q = blockIdx.x * blockDim.x + threadIdx.x;      // one int4 per thread
    int n4 = nAtoms >> 2;
    if (q >= n4) return;
    int a0 = q << 2;
    int b  = a0 >> BSH;
    int li = a0 & BMASK;
    long base = (long)(b * SCH) * (1 << BSH) + li;
    int4 s = {0, 0, 0, 0};
#pragma unroll
    for (int r = 0; r < SCH; ++r) {
        int4 p = *reinterpret_cast<const int4*>(partials + base + (long)r * (1 << BSH));
        s.x += p.x; s.y += p.y; s.z += p.z; s.w += p.w;
    }
    float4 qv = reinterpret_cast<const float4*>(Qa)[q];
    float4 sp = reinterpret_cast<const float4*>(out)[q];   // spill (or 0)
    float4 o;
    o.x = KEHALF * qv.x * ((float)s.x * VINV) + sp.x;
    o.y = KEHALF * qv.y * ((float)s.y * VINV) + sp.y;
    o.z = KEHALF * qv.z * ((float)s.z * VINV) + sp.z;
    o.w = KEHALF * qv.w * ((float)s.w * VINV) + sp.w;
    reinterpret_cast<float4*>(out)[q] = o;
}

// ---------------- Fallback: int fixed-point global atomics (R3) --------
#define FP_SCALE 4194304.0f
#define FP_INV   (1.0f / 4194304.0f)

__device__ __forceinline__ float radial_exact(float d) {
    float dsh = sqrtf(d * d + 1.0f);
    float x   = 0.5f * d;
    float sw  = (x < 1.0f) ? 1.0f - x * x * x * (x * (6.0f * x - 15.0f) + 10.0f)
                           : 0.0f;
    float Eo = 1.0f / d   + d   * 0.01f - 0.2f;
    float Es = 1.0f / dsh + dsh * 0.01f - 0.2f;
    return sw * Es + (1.0f - sw) * Eo;
}

__global__ __launch_bounds__(256) void ee_pair_fix(
    const float* __restrict__ Dij,
    const float* __restrict__ Qa,
    const int*   __restrict__ idx_i,
    const int*   __restrict__ idx_j,
    int*         __restrict__ acc,
    int P)
{
    long base = ((long)blockIdx.x * blockDim.x + threadIdx.x) * 4;
    if (base >= P) return;
    float4 d4 = *reinterpret_cast<const float4*>(Dij + base);
    int4   i4 = *reinterpret_cast<const int4*>(idx_i + base);
    int4   j4 = *reinterpret_cast<const int4*>(idx_j + base);
    float D[4]  = {d4.x, d4.y, d4.z, d4.w};
    int   ii[4] = {i4.x, i4.y, i4.z, i4.w};
    int   jj[4] = {j4.x, j4.y, j4.z, j4.w};
#pragma unroll
    for (int k = 0; k < 4; ++k) {
        float d = D[k];
        if (d > 10.0f) continue;
        float e = KEHALF * Qa[ii[k]] * Qa[jj[k]] * radial_exact(d);
        atomicAdd(acc + ii[k], __float2int_rn(e * FP_SCALE));
    }
}

__global__ __launch_bounds__(256) void ee_convert(
    const int* __restrict__ acc, float* __restrict__ out, int nAtoms)
{
    int n4 = nAtoms >> 2;
    int q = blockIdx.x * blockDim.x + threadIdx.x;
    if (q >= n4) return;
    int4 a = reinterpret_cast<const int4*>(acc)[q];
    float4 o;
    o.x = (float)a.x * FP_INV;
    o.y = (float)a.y * FP_INV;
    o.z = (float)a.z * FP_INV;
    o.w = (float)a.w * FP_INV;
    reinterpret_cast<float4*>(out)[q] = o;
}

__global__ __launch_bounds__(256) void ee_pair_direct(
    const float* __restrict__ Dij,
    const float* __restrict__ Qa,
    const int*   __restrict__ idx_i,
    const int*   __restrict__ idx_j,
    float*       __restrict__ out,
    int P)
{
    long t = (long)blockIdx.x * blockDim.x + threadIdx.x;
    if (t >= P) return;
    float d = Dij[t];
    if (d > 10.0f) return;
    atomicAdd(out + idx_i[t], KEHALF * Qa[idx_i[t]] * Qa[idx_j[t]] * radial_exact(d));
}

extern "C" void kernel_launch(void* const* d_in, const int* in_sizes, int n_in,
                              void* d_out, int out_size, void* d_ws, size_t ws_size,
                              hipStream_t stream) {
    const float* Dij   = (const float*)d_in[0];
    const float* Qa    = (const float*)d_in[1];
    const int*   idx_i = (const int*)d_in[2];
    const int*   idx_j = (const int*)d_in[3];
    float*       out   = (float*)d_out;

    int P      = in_sizes[0];
    int nAtoms = in_sizes[1];

    size_t listBytes = (size_t)NB * CAP * sizeof(unsigned int);          // ~55.9 MiB
    size_t partBytes = (size_t)NB * SCH * (1 << BSH) * sizeof(int);      // 8 MiB
    size_t curBytes  = (size_t)NB * NREP * CURSTRIDE * sizeof(unsigned int); // 64 KiB

    if (ws_size >= listBytes + partBytes + curBytes &&
        nAtoms == NB * (1 << BSH) && (P % P1PAIRS) == 0) {
        unsigned int* list = (unsigned int*)d_ws;
        int*          part = (int*)((char*)d_ws + listBytes);
        unsigned int* gcur = (unsigned int*)((char*)d_ws + listBytes + partBytes);
        hipMemsetAsync(gcur, 0, curBytes, stream);
        hipMemsetAsync(out, 0, (size_t)out_size * sizeof(float), stream); // spill base
        int grid1 = P / P1PAIRS;                                          // 2048
        ee_bin<<<grid1, P1B, 0, stream>>>(Dij, Qa, idx_i, idx_j, list, gcur, out);
        ee_acc<<<NB * SCH, 512, 0, stream>>>(list, gcur, part);
        ee_final<<<(nAtoms / 4 + 255) / 256, 256, 0, stream>>>(part, Qa, out, nAtoms);
    } else if (ws_size >= (size_t)nAtoms * sizeof(int) &&
               (nAtoms & 3) == 0 && (P & 3) == 0) {
        int* acc = (int*)d_ws;
        hipMemsetAsync(acc, 0, (size_t)nAtoms * sizeof(int), stream);
        int grid = (P / 4 + 255) / 256;
        ee_pair_fix<<<grid, 256, 0, stream>>>(Dij, Qa, idx_i, idx_j, acc, P);
        ee_convert<<<(nAtoms / 4 + 255) / 256, 256, 0, stream>>>(acc, out, nAtoms);
    } else {
        hipMemsetAsync(out, 0, (size_t)out_size * sizeof(float), stream);
        int grid = (P + 255) / 256;
        ee_pair_direct<<<grid, 256, 0, stream>>>(Dij, Qa, idx_i, idx_j, out, P);
    }
}